// Round 14
// baseline (174.313 us; speedup 1.0000x reference)
//
#include <hip/hip_runtime.h>
#include <hip/hip_bf16.h>
#include <math.h>

#define T_SEQ 2048
#define NHEAD 16
#define DQK 192      // NOPE + ROPE
#define DNOPE 128
#define DROPE 64
#define LORA_D 512
#define VDIM 128
#define SCALE_F 0.072168783648703216f  // 1/sqrt(192)
// flash R14: KC=64 kv-chunks. Split-K table (R6 structure, 64-unit chunks):
// per head, tile j (q0=j*64) has n_j = j+1 chunks, s_j = ceil(n_j/8):
// j 0..7 -> 1 (direct), 8..15 -> 2, 16..23 -> 3, 24..31 -> 4.
// blocks/head = 80; slots/head = 72; grid 1280 — all identical to R11/R13.
// R12 ERRATUM stands: no device-scope fences inside flash (L2 wipe, 2x cost).

typedef short bf16x8 __attribute__((ext_vector_type(8)));   // 8 bf16 = 4 VGPRs
typedef float f32x4 __attribute__((ext_vector_type(4)));

static __device__ __forceinline__ unsigned short f2bf(float x) {
  union { float f; unsigned int u; } v; v.f = x;
  unsigned int r = (v.u + 0x7fff + ((v.u >> 16) & 1)) >> 16;  // RNE
  return (unsigned short)r;
}

// ---------------------------------------------------------------------------
// stage_all: fused input prep. grid (1024, 3).  [proven]
// ---------------------------------------------------------------------------
__global__ __launch_bounds__(256) void stage_all(
    const float* __restrict__ k_c, const float* __restrict__ w_kv_b,
    const float* __restrict__ w_uv, unsigned short* __restrict__ Ab,
    unsigned short* __restrict__ BkT, unsigned short* __restrict__ BvT)
{
  __shared__ float tile[32][33];
  const int bx = blockIdx.x, role = blockIdx.y;
  const int tid = threadIdx.x;
  if (role == 0) {
    int i = (bx * 256 + tid) * 4;
    float4 v = *(const float4*)(k_c + i);
    ushort4 o = {f2bf(v.x), f2bf(v.y), f2bf(v.z), f2bf(v.w)};
    *(ushort4*)(Ab + i) = o;
    return;
  }
  const int tk = tid >> 3, tc4 = (tid & 7) * 4;
  const int wr = tid >> 3, wk4 = (tid & 7) * 4;
  if (role == 1) {
    const int k0 = (bx & 15) * 32, n0 = (bx >> 4) * 32;
    int n = n0 + tc4;
    int col = n + ((n >> 7) << 7);   // skip VDIM half of each head's 256 cols
    float4 v = *(const float4*)&w_kv_b[(size_t)(k0 + tk) * 4096 + col];
    tile[tk][tc4 + 0] = v.x; tile[tk][tc4 + 1] = v.y;
    tile[tk][tc4 + 2] = v.z; tile[tk][tc4 + 3] = v.w;
    __syncthreads();
    ushort4 o = {f2bf(tile[wk4 + 0][wr]), f2bf(tile[wk4 + 1][wr]),
                 f2bf(tile[wk4 + 2][wr]), f2bf(tile[wk4 + 3][wr])};
    *(ushort4*)&BkT[(size_t)(n0 + wr) * LORA_D + k0 + wk4] = o;
  } else {
    const int k0 = (bx & 15) * 32, v0 = ((bx >> 4) & 3) * 32, h = bx >> 6;
    float4 v = *(const float4*)&w_uv[(size_t)h * 65536 + (size_t)(k0 + tk) * 128 + v0 + tc4];
    tile[tk][tc4 + 0] = v.x; tile[tk][tc4 + 1] = v.y;
    tile[tk][tc4 + 2] = v.z; tile[tk][tc4 + 3] = v.w;
    __syncthreads();
    ushort4 o = {f2bf(tile[wk4 + 0][wr]), f2bf(tile[wk4 + 1][wr]),
                 f2bf(tile[wk4 + 2][wr]), f2bf(tile[wk4 + 3][wr])};
    *(ushort4*)&BvT[(size_t)(h * VDIM + v0 + wr) * LORA_D + k0 + wk4] = o;
  }
}

// ---------------------------------------------------------------------------
// prep_gemm: R7/R8-proven async version. BK=64 dbuf via global_load_lds,
// XOR-swizzled LDS rows, coalesced LDS-staged epilogues.
// ---------------------------------------------------------------------------
__global__ __launch_bounds__(256) void prep_gemm(
    const unsigned short* __restrict__ A, const unsigned short* __restrict__ BkT,
    const unsigned short* __restrict__ BvT, const float* __restrict__ k_pe,
    unsigned short* __restrict__ Kb, unsigned short* __restrict__ Vt)
{
  __shared__ unsigned short SMEM[32768];
  const int m0 = blockIdx.x * 128;
  const int by = blockIdx.y;
  const int isK = (by < 16);
  const int n0 = (isK ? by : (by - 16)) * 128;
  const unsigned short* BT = isK ? BkT : BvT;
  const int tid = threadIdx.x;
  const int wid = tid >> 6, lane = tid & 63;
  const int l16 = lane & 15, quad = lane >> 4;
  const int wm = (wid >> 1) * 64, wn = (wid & 1) * 64;

  auto stage_pg = [&](int b, int k0) {
    const char* Asrc = (const char*)(A + (size_t)m0 * LORA_D + k0);
    const char* Bsrc = (const char*)(BT + (size_t)n0 * LORA_D + k0);
    char* Adst = (char*)SMEM + b * 16384;
    char* Bdst = (char*)SMEM + 32768 + b * 16384;
#pragma unroll
    for (int i = 0; i < 4; ++i) {
      int d = tid * 16 + i * 4096;
      int row = d >> 7, c = d & 127;
      int sc = c ^ ((row & 7) << 4);
      __builtin_amdgcn_global_load_lds(
          (const unsigned int*)(Asrc + (size_t)row * 1024 + sc),
          (unsigned int*)(Adst + d), 16, 0, 0);
      __builtin_amdgcn_global_load_lds(
          (const unsigned int*)(Bsrc + (size_t)row * 1024 + sc),
          (unsigned int*)(Bdst + d), 16, 0, 0);
    }
  };

  f32x4 acc[4][4];
#pragma unroll
  for (int i = 0; i < 4; ++i)
#pragma unroll
    for (int j = 0; j < 4; ++j) acc[i][j] = (f32x4){0.f, 0.f, 0.f, 0.f};

  stage_pg(0, 0);
  __syncthreads();
  for (int kc = 0; kc < 8; ++kc) {
    const int cur = kc & 1;
    if (kc < 7) stage_pg(cur ^ 1, (kc + 1) * 64);
#pragma unroll
    for (int kk = 0; kk < 2; ++kk) {
      bf16x8 af[4], bfr[4];
#pragma unroll
      for (int t = 0; t < 4; ++t) {
        int ra = wm + t * 16 + l16;
        af[t] = *(const bf16x8*)((char*)SMEM + cur * 16384 + ra * 128 +
                                 (((kk * 4 + quad) ^ (ra & 7)) << 4));
        int rb = wn + t * 16 + l16;
        bfr[t] = *(const bf16x8*)((char*)SMEM + 32768 + cur * 16384 + rb * 128 +
                                  (((kk * 4 + quad) ^ (rb & 7)) << 4));
      }
#pragma unroll
      for (int mt = 0; mt < 4; ++mt)
#pragma unroll
        for (int nt = 0; nt < 4; ++nt)
          acc[mt][nt] = __builtin_amdgcn_mfma_f32_16x16x32_bf16(af[mt], bfr[nt], acc[mt][nt], 0, 0, 0);
    }
    __syncthreads();
  }

  unsigned short* E = SMEM;   // [128][136]
  if (isK) {
#pragma unroll
    for (int mt = 0; mt < 4; ++mt)
#pragma unroll
      for (int nt = 0; nt < 4; ++nt) {
        int ml = wm + mt * 16 + quad * 4;
        int d = wn + nt * 16 + l16;
#pragma unroll
        for (int r = 0; r < 4; ++r)
          E[(ml + r) * 136 + d] = f2bf(acc[mt][nt][r]);
      }
  } else {
#pragma unroll
    for (int mt = 0; mt < 4; ++mt)
#pragma unroll
      for (int nt = 0; nt < 4; ++nt) {
        int ml = wm + mt * 16 + quad * 4;
        int nl = wn + nt * 16 + l16;
#pragma unroll
        for (int r = 0; r < 4; ++r)
          E[nl * 136 + ml + r] = f2bf(acc[mt][nt][r]);
      }
  }
  __syncthreads();

  if (isK) {
    const int h = by;
#pragma unroll
    for (int i = 0; i < 8; ++i) {
      int idx = (i * 256 + tid) * 8;
      int row = idx >> 7, col = idx & 127;
      uint4 v = *(const uint4*)&E[row * 136 + col];
      *(uint4*)&Kb[(size_t)h * (T_SEQ * DQK) + (size_t)(m0 + row) * DQK + col] = v;
    }
    for (int e = tid; e < 128 * 16; e += 256) {
      int row = e >> 4, c4 = (e & 15) * 4;
      float4 v = *(const float4*)&k_pe[(size_t)(m0 + row) * DROPE + c4];
      ushort4 o = {f2bf(v.x), f2bf(v.y), f2bf(v.z), f2bf(v.w)};
      *(ushort4*)&Kb[(size_t)h * (T_SEQ * DQK) + (size_t)(m0 + row) * DQK + DNOPE + c4] = o;
    }
  } else {
#pragma unroll
    for (int i = 0; i < 8; ++i) {
      int idx = (i * 256 + tid) * 8;
      int row = idx >> 7, col = idx & 127;
      uint4 v = *(const uint4*)&E[row * 136 + col];
      *(uint4*)&Vt[(size_t)(n0 + row) * T_SEQ + m0 + col] = v;
    }
  }
}

// ---------------------------------------------------------------------------
// flash_mfma R14: R11 pipeline with KC=64 kv-chunks. Doubling the KV axis
// (not q, which sank R7: oacc scales with q-rows) doubles MFMA/barrier
// (40/wave) with only ~+24 transient VGPRs. Barriers halve (16896->8448
// chunk-rounds). sigma staging extended to 4 row-groups: LDS row rho holds
// global kv ((rho>>5)<<5) + 8*((rho&15)>>2) + 2*(rho&3) + ((rho>>4)&1), so
// sacc0..3[r] -> kv quad*8+2r {+0,+1,+32,+33} and BOTH PV A-fragments form
// with zero cross-lane ops (4+4 cvt_pk). V rows now 128 B: (row&7)<<4 XOR
// spreads 8 ways -> 2-way conflicts (was 4-way at 64 B rows). LDS 80 KB ->
// 2 blocks/CU (R10 falsifier: occupancy does not bind this kernel).
// ---------------------------------------------------------------------------
__global__ __launch_bounds__(256, 2) void flash_mfma(
    const float* __restrict__ Q, const unsigned short* __restrict__ K,
    const unsigned short* __restrict__ Vt, float* __restrict__ outp,
    float* __restrict__ Opart, float* __restrict__ Lpart, int adaptive)
{
  __shared__ unsigned short SM[2 * 64 * DQK];     // K dbuf [2][64][192]; Q stage [64][192]
  __shared__ unsigned short Vsm[2 * VDIM * 64];   // V dbuf [2][128][64]
  const int id = blockIdx.x;
  const int h = ((id & 7) << 1) | ((id >> 3) & 1);   // cluster heads per XCD
  int q0, c0, c1, slot, direct;
  if (adaptive) {
    const int b = 79 - (id >> 4);                    // heavy splits first
    int j, sp, s;
    if (b < 8)       { j = b;               sp = 0;            s = 1; }
    else if (b < 24) { j = 8 + (b - 8) / 2; sp = (b - 8) % 2;  s = 2; }
    else if (b < 48) { j = 16 + (b - 24) / 3; sp = (b - 24) % 3; s = 3; }
    else             { j = 24 + (b - 48) / 4; sp = (b - 48) % 4; s = 4; }
    q0 = j * 64;
    const int n = j + 1;                             // chunks of 64 kv
    c0 = (n * sp) / s;
    c1 = (n * (sp + 1)) / s;
    direct = (s == 1);
    slot = h * 72 + (b - 8);                         // valid iff !direct
  } else {
    q0 = (31 - (id >> 4)) * 64;
    c0 = 0; c1 = q0 / 64 + 1; direct = 1; slot = 0;
  }
  const int tid = threadIdx.x;
  const int wid = tid >> 6;
  const int lane = tid & 63;
  const int l16 = lane & 15;
  const int quad = lane >> 4;
  const int myrow = q0 + wid * 16 + quad * 4;        // output-row base (D rows)
  const int qrow  = q0 + wid * 16 + l16;             // this lane's q in S^T
  const int nch = c1 - c0;                           // >= 1 always

  const unsigned short* Kh = K + (size_t)h * T_SEQ * DQK;
  const unsigned short* Vth = Vt + (size_t)h * VDIM * T_SEQ;

  // ---- precomputed per-thread staging offsets. K: sigma row permutation +
  //      inverse XOR on SOURCE; V: 128-B rows, (row&7)<<4 XOR. ----
  int ksrc_off[6], kdst_off[6];
#pragma unroll
  for (int i = 0; i < 6; ++i) {
    int d = tid * 16 + i * 4096;
    int rho = d / 384, c = d - rho * 384;
    int rp = rho & 15, grp = rho >> 4;
    int g = ((grp >> 1) << 5) + 8 * (rp >> 2) + 2 * (rp & 3) + (grp & 1);
    ksrc_off[i] = g * 384 + (c ^ ((rho & 7) << 4));
    kdst_off[i] = d;
  }
  size_t vsrc_off[4]; int vdst_off[4];
#pragma unroll
  for (int i = 0; i < 4; ++i) {
    int d = tid * 16 + i * 4096;
    int row = d >> 7, c = d & 127;
    vsrc_off[i] = (size_t)row * (T_SEQ * 2) + (c ^ ((row & 7) << 4));
    vdst_off[i] = d;
  }

  auto stage = [&](int buf, int s0) {
    const char* Kc = (const char*)Kh + (size_t)s0 * 384;
    char* Kd = (char*)&SM[buf * (64 * DQK)];
#pragma unroll
    for (int i = 0; i < 6; ++i)
      __builtin_amdgcn_global_load_lds(
          (const unsigned int*)(Kc + ksrc_off[i]),
          (unsigned int*)(Kd + kdst_off[i]), 16, 0, 0);
    const char* Vc = (const char*)Vth + (size_t)s0 * 2;
    char* Vd = (char*)&Vsm[buf * (VDIM * 64)];
#pragma unroll
    for (int i = 0; i < 4; ++i)
      __builtin_amdgcn_global_load_lds(
          (const unsigned int*)(Vc + vsrc_off[i]),
          (unsigned int*)(Vd + vdst_off[i]), 16, 0, 0);
  };

  // ---- stage Q through the K-dbuf region (64*192 shorts = buf 0 exactly) --
  for (int e = tid; e < 64 * 48; e += 256) {
    int row = e / 48, col = (e % 48) * 4;
    float4 q4 = *(const float4*)&Q[(size_t)(q0 + row) * (NHEAD * DQK) + h * DQK + col];
    ushort4 qp = {f2bf(q4.x), f2bf(q4.y), f2bf(q4.z), f2bf(q4.w)};
    *(ushort4*)&SM[row * DQK + col] = qp;
  }
  __syncthreads();
  bf16x8 qf[6];
#pragma unroll
  for (int ks = 0; ks < 6; ++ks)
    qf[ks] = *(const bf16x8*)&SM[(wid * 16 + l16) * DQK + ks * 32 + quad * 8];
  __syncthreads();           // Q reads done before region becomes K buffers
  stage(0, c0 * 64);         // async chunk 0
  __syncthreads();           // drains vmcnt(0): buffer 0 visible

  f32x4 oacc[8];
#pragma unroll
  for (int i = 0; i < 8; ++i) oacc[i] = (f32x4){0.f, 0.f, 0.f, 0.f};
  float lsum = 0.f;          // per-lane: all kv for q = qrow (kv on quad axis)

  for (int ck = 0; ck < nch; ++ck) {
    const int cur = ck & 1;
    const int s0 = (c0 + ck) * 64;
    if (ck + 1 < nch) stage(cur ^ 1, s0 + 64);   // async, in flight all chunk

    // ---- S^T = K @ Q^T over 64 kv (4 row-groups; same XOR all groups) ----
    const char* Kbase = (const char*)&SM[cur * (64 * DQK)];
    f32x4 sa0 = (f32x4){0.f, 0.f, 0.f, 0.f};
    f32x4 sa1 = (f32x4){0.f, 0.f, 0.f, 0.f};
    f32x4 sa2 = (f32x4){0.f, 0.f, 0.f, 0.f};
    f32x4 sa3 = (f32x4){0.f, 0.f, 0.f, 0.f};
    __builtin_amdgcn_s_setprio(1);
#pragma unroll
    for (int ks = 0; ks < 6; ++ks) {
      int cx = (ks * 64 + quad * 16) ^ ((l16 & 7) << 4);
      bf16x8 kf0 = *(const bf16x8*)(Kbase + (l16)      * 384 + cx);
      bf16x8 kf1 = *(const bf16x8*)(Kbase + (16 + l16) * 384 + cx);
      bf16x8 kf2 = *(const bf16x8*)(Kbase + (32 + l16) * 384 + cx);
      bf16x8 kf3 = *(const bf16x8*)(Kbase + (48 + l16) * 384 + cx);
      sa0 = __builtin_amdgcn_mfma_f32_16x16x32_bf16(kf0, qf[ks], sa0, 0, 0, 0);
      sa1 = __builtin_amdgcn_mfma_f32_16x16x32_bf16(kf1, qf[ks], sa1, 0, 0, 0);
      sa2 = __builtin_amdgcn_mfma_f32_16x16x32_bf16(kf2, qf[ks], sa2, 0, 0, 0);
      sa3 = __builtin_amdgcn_mfma_f32_16x16x32_bf16(kf3, qf[ks], sa3, 0, 0, 0);
    }
    __builtin_amdgcn_s_setprio(0);

    // ---- p = exp(s), mask via p=0. sigma: sa0[r]->kv s0+quad*8+2r,
    //      sa1->+1, sa2->+32, sa3->+33. Pack both PV A-fragments. ----
    union { unsigned int u[4]; bf16x8 v; } plo, phi;
#pragma unroll
    for (int r = 0; r < 4; ++r) {
      int kva = s0 + quad * 8 + 2 * r;
      float e0 = (kva <= qrow)      ? __expf(sa0[r] * SCALE_F) : 0.f;
      float e1 = (kva + 1 <= qrow)  ? __expf(sa1[r] * SCALE_F) : 0.f;
      float e2 = (kva + 32 <= qrow) ? __expf(sa2[r] * SCALE_F) : 0.f;
      float e3 = (kva + 33 <= qrow) ? __expf(sa3[r] * SCALE_F) : 0.f;
      lsum += (e0 + e1) + (e2 + e3);
      asm("v_cvt_pk_bf16_f32 %0, %1, %2" : "=v"(plo.u[r]) : "v"(e0), "v"(e1));
      asm("v_cvt_pk_bf16_f32 %0, %1, %2" : "=v"(phi.u[r]) : "v"(e2), "v"(e3));
    }
    bf16x8 pflo = plo.v, pfhi = phi.v;

    // ---- PV: two k-halves per nt (kv 0..31 and 32..63 of the chunk) ----
    const char* Vbase = (const char*)&Vsm[cur * (VDIM * 64)];
    __builtin_amdgcn_s_setprio(1);
#pragma unroll
    for (int nt = 0; nt < 8; ++nt) {
      int vrow = nt * 16 + l16;
      int swz = (vrow & 7) << 4;
      bf16x8 vlo = *(const bf16x8*)(Vbase + vrow * 128 + ((quad * 16) ^ swz));
      bf16x8 vhi = *(const bf16x8*)(Vbase + vrow * 128 + ((64 + quad * 16) ^ swz));
      oacc[nt] = __builtin_amdgcn_mfma_f32_16x16x32_bf16(pflo, vlo, oacc[nt], 0, 0, 0);
      oacc[nt] = __builtin_amdgcn_mfma_f32_16x16x32_bf16(pfhi, vhi, oacc[nt], 0, 0, 0);
    }
    __builtin_amdgcn_s_setprio(0);

    __syncthreads();   // drains vmcnt (next-chunk stage) + lgkm; flip buffers
  }

  // ---- reduce lsum across quads (kv axis); all quads then hold q=l16 total --
  lsum += __shfl_xor(lsum, 16);
  lsum += __shfl_xor(lsum, 32);
  // redistribute to output-row layout: row r of this lane is q = quad*4+r
  float rowsum[4];
#pragma unroll
  for (int r = 0; r < 4; ++r) rowsum[r] = __shfl(lsum, quad * 4 + r, 64);

  if (direct) {
    float inv[4];
#pragma unroll
    for (int r = 0; r < 4; ++r) inv[r] = 1.f / rowsum[r];
#pragma unroll
    for (int nt = 0; nt < 8; ++nt)
#pragma unroll
      for (int r = 0; r < 4; ++r)
        outp[(size_t)(myrow + r) * (NHEAD * VDIM) + h * VDIM + nt * 16 + l16] =
            oacc[nt][r] * inv[r];
  } else {
    // dense block-local partial slot: [64][128] fp32, fully-written lines
    const int rbase = wid * 16 + quad * 4;
#pragma unroll
    for (int nt = 0; nt < 8; ++nt)
#pragma unroll
      for (int r = 0; r < 4; ++r)
        Opart[(size_t)slot * 8192 + (rbase + r) * 128 + nt * 16 + l16] =
            oacc[nt][r];
    if (l16 == 0)
#pragma unroll
      for (int r = 0; r < 4; ++r)
        Lpart[slot * 64 + rbase + r] = rowsum[r];
  }
}

// ---------------------------------------------------------------------------
// reduce_out: combine partial slots for split tiles (j >= 8 only).
// ---------------------------------------------------------------------------
__global__ __launch_bounds__(256) void reduce_out(
    const float* __restrict__ Opart, const float* __restrict__ Lpart,
    float* __restrict__ outp)
{
  const int t = blockIdx.x;
  const int h = t & 15;
  const int j = 8 + (t >> 4);
  int s, b0;
  if (j < 16)      { s = 2; b0 = 8 + (j - 8) * 2; }
  else if (j < 24) { s = 3; b0 = 24 + (j - 16) * 3; }
  else             { s = 4; b0 = 48 + (j - 24) * 4; }
  const int slot = h * 72 + (b0 - 8);
  const int q0 = j * 64;
  const int tid = threadIdx.x;
#pragma unroll
  for (int i = 0; i < 8; ++i) {
    const int f4 = tid + i * 256;            // [0,2048) float4 within tile
    const int row = f4 >> 5, cc = f4 & 31;
    float ax = 0.f, ay = 0.f, az = 0.f, aw = 0.f, l = 0.f;
    for (int k = 0; k < s; ++k) {
      float4 v = ((const float4*)Opart)[(size_t)(slot + k) * 2048 + f4];
      ax += v.x; ay += v.y; az += v.z; aw += v.w;
      l += Lpart[(slot + k) * 64 + row];
    }
    const float inv = 1.f / l;
    float4 o = {ax * inv, ay * inv, az * inv, aw * inv};
    ((float4*)outp)[(size_t)(q0 + row) * 512 + h * 32 + cc] = o;
  }
}

// ---------------------------------------------------------------------------
extern "C" void kernel_launch(void* const* d_in, const int* in_sizes, int n_in,
                              void* d_out, int out_size, void* d_ws, size_t ws_size,
                              hipStream_t stream) {
  const float* query  = (const float*)d_in[0];  // (T, H, 192)
  const float* k_c    = (const float*)d_in[1];  // (T, 512)
  const float* k_pe   = (const float*)d_in[2];  // (T, 64)
  const float* w_kv_b = (const float*)d_in[3];  // (512, 4096)
  const float* w_uv   = (const float*)d_in[4];  // (16, 512, 128)
  float* outp = (float*)d_out;                  // (T, 2048)

  unsigned short* Kb  = (unsigned short*)d_ws;             // (H,T,192) bf16
  unsigned short* Vt  = Kb + (size_t)NHEAD * T_SEQ * DQK;  // (H,128,T) bf16
  unsigned short* Ab  = Vt + (size_t)NHEAD * VDIM * T_SEQ; // (T,512)
  unsigned short* BkT = Ab + (size_t)T_SEQ * LORA_D;       // (2048,512)
  unsigned short* BvT = BkT + (size_t)2048 * LORA_D;       // (2048,512)
  float* Opart = (float*)(BvT + (size_t)2048 * LORA_D);    // 1152 x [64][128] fp32
  float* Lpart = Opart + (size_t)16 * 72 * 64 * 128;       // 1152 x [64] fp32
  const size_t need =
      (size_t)((char*)(Lpart + (size_t)16 * 72 * 64) - (char*)d_ws);
  const int adaptive = (ws_size >= need) ? 1 : 0;   // safe fallback

  stage_all<<<dim3(1024, 3), 256, 0, stream>>>(k_c, w_kv_b, w_uv, Ab, BkT, BvT);
  prep_gemm<<<dim3(16, 32), 256, 0, stream>>>(Ab, BkT, BvT, k_pe, Kb, Vt);
  flash_mfma<<<adaptive ? 1280 : 512, 256, 0, stream>>>(query, Kb, Vt, outp,
                                                        Opart, Lpart, adaptive);
  if (adaptive)
    reduce_out<<<384, 256, 0, stream>>>(Opart, Lpart, outp);
}

// Round 15
// 163.490 us; speedup vs baseline: 1.0662x; 1.0662x over previous
//
#include <hip/hip_runtime.h>
#include <hip/hip_bf16.h>
#include <math.h>

#define T_SEQ 2048
#define NHEAD 16
#define DQK 192      // NOPE + ROPE
#define DNOPE 128
#define DROPE 64
#define LORA_D 512
#define VDIM 128
#define SCALE_F 0.072168783648703216f  // 1/sqrt(192)
#define KC 32
// adaptive split-K (R6-proven): each block <= 16 chunks. Per head, tile j
// (q0 = j*64) has n_j = 2j+2 chunks, s_j = ceil(n_j/16) splits:
// j 0..7 -> 1 (direct store), 8..15 -> 2, 16..23 -> 3, 24..31 -> 4.
// blocks/head = 80; partial slots/head = 72. Grid 1280.
// Session ledger (measured):
//  R12 ERRATUM: device-scope fences inside flash wipe per-XCD L2 (169->355).
//  R14 ERRATUM: KC=64 killed conflicts 7x but 2 blocks/CU < overlap knee
//  (62->70). Occupancy knee is ~3 resident blocks; conflicts non-binding.
//  R15 = exact R13/R11 restore: session-best (total 167.0, flash 60-62).

typedef short bf16x8 __attribute__((ext_vector_type(8)));   // 8 bf16 = 4 VGPRs
typedef float f32x4 __attribute__((ext_vector_type(4)));

static __device__ __forceinline__ unsigned short f2bf(float x) {
  union { float f; unsigned int u; } v; v.f = x;
  unsigned int r = (v.u + 0x7fff + ((v.u >> 16) & 1)) >> 16;  // RNE
  return (unsigned short)r;
}

// ---------------------------------------------------------------------------
// stage_all: fused input prep. grid (1024, 3).  [proven]
// ---------------------------------------------------------------------------
__global__ __launch_bounds__(256) void stage_all(
    const float* __restrict__ k_c, const float* __restrict__ w_kv_b,
    const float* __restrict__ w_uv, unsigned short* __restrict__ Ab,
    unsigned short* __restrict__ BkT, unsigned short* __restrict__ BvT)
{
  __shared__ float tile[32][33];
  const int bx = blockIdx.x, role = blockIdx.y;
  const int tid = threadIdx.x;
  if (role == 0) {
    int i = (bx * 256 + tid) * 4;
    float4 v = *(const float4*)(k_c + i);
    ushort4 o = {f2bf(v.x), f2bf(v.y), f2bf(v.z), f2bf(v.w)};
    *(ushort4*)(Ab + i) = o;
    return;
  }
  const int tk = tid >> 3, tc4 = (tid & 7) * 4;
  const int wr = tid >> 3, wk4 = (tid & 7) * 4;
  if (role == 1) {
    const int k0 = (bx & 15) * 32, n0 = (bx >> 4) * 32;
    int n = n0 + tc4;
    int col = n + ((n >> 7) << 7);   // skip VDIM half of each head's 256 cols
    float4 v = *(const float4*)&w_kv_b[(size_t)(k0 + tk) * 4096 + col];
    tile[tk][tc4 + 0] = v.x; tile[tk][tc4 + 1] = v.y;
    tile[tk][tc4 + 2] = v.z; tile[tk][tc4 + 3] = v.w;
    __syncthreads();
    ushort4 o = {f2bf(tile[wk4 + 0][wr]), f2bf(tile[wk4 + 1][wr]),
                 f2bf(tile[wk4 + 2][wr]), f2bf(tile[wk4 + 3][wr])};
    *(ushort4*)&BkT[(size_t)(n0 + wr) * LORA_D + k0 + wk4] = o;
  } else {
    const int k0 = (bx & 15) * 32, v0 = ((bx >> 4) & 3) * 32, h = bx >> 6;
    float4 v = *(const float4*)&w_uv[(size_t)h * 65536 + (size_t)(k0 + tk) * 128 + v0 + tc4];
    tile[tk][tc4 + 0] = v.x; tile[tk][tc4 + 1] = v.y;
    tile[tk][tc4 + 2] = v.z; tile[tk][tc4 + 3] = v.w;
    __syncthreads();
    ushort4 o = {f2bf(tile[wk4 + 0][wr]), f2bf(tile[wk4 + 1][wr]),
                 f2bf(tile[wk4 + 2][wr]), f2bf(tile[wk4 + 3][wr])};
    *(ushort4*)&BvT[(size_t)(h * VDIM + v0 + wr) * LORA_D + k0 + wk4] = o;
  }
}

// ---------------------------------------------------------------------------
// prep_gemm: R7/R8-proven async version. BK=64 dbuf via global_load_lds,
// XOR-swizzled LDS rows, coalesced LDS-staged epilogues.
// ---------------------------------------------------------------------------
__global__ __launch_bounds__(256) void prep_gemm(
    const unsigned short* __restrict__ A, const unsigned short* __restrict__ BkT,
    const unsigned short* __restrict__ BvT, const float* __restrict__ k_pe,
    unsigned short* __restrict__ Kb, unsigned short* __restrict__ Vt)
{
  __shared__ unsigned short SMEM[32768];
  const int m0 = blockIdx.x * 128;
  const int by = blockIdx.y;
  const int isK = (by < 16);
  const int n0 = (isK ? by : (by - 16)) * 128;
  const unsigned short* BT = isK ? BkT : BvT;
  const int tid = threadIdx.x;
  const int wid = tid >> 6, lane = tid & 63;
  const int l16 = lane & 15, quad = lane >> 4;
  const int wm = (wid >> 1) * 64, wn = (wid & 1) * 64;

  auto stage_pg = [&](int b, int k0) {
    const char* Asrc = (const char*)(A + (size_t)m0 * LORA_D + k0);
    const char* Bsrc = (const char*)(BT + (size_t)n0 * LORA_D + k0);
    char* Adst = (char*)SMEM + b * 16384;
    char* Bdst = (char*)SMEM + 32768 + b * 16384;
#pragma unroll
    for (int i = 0; i < 4; ++i) {
      int d = tid * 16 + i * 4096;
      int row = d >> 7, c = d & 127;
      int sc = c ^ ((row & 7) << 4);
      __builtin_amdgcn_global_load_lds(
          (const unsigned int*)(Asrc + (size_t)row * 1024 + sc),
          (unsigned int*)(Adst + d), 16, 0, 0);
      __builtin_amdgcn_global_load_lds(
          (const unsigned int*)(Bsrc + (size_t)row * 1024 + sc),
          (unsigned int*)(Bdst + d), 16, 0, 0);
    }
  };

  f32x4 acc[4][4];
#pragma unroll
  for (int i = 0; i < 4; ++i)
#pragma unroll
    for (int j = 0; j < 4; ++j) acc[i][j] = (f32x4){0.f, 0.f, 0.f, 0.f};

  stage_pg(0, 0);
  __syncthreads();
  for (int kc = 0; kc < 8; ++kc) {
    const int cur = kc & 1;
    if (kc < 7) stage_pg(cur ^ 1, (kc + 1) * 64);
#pragma unroll
    for (int kk = 0; kk < 2; ++kk) {
      bf16x8 af[4], bfr[4];
#pragma unroll
      for (int t = 0; t < 4; ++t) {
        int ra = wm + t * 16 + l16;
        af[t] = *(const bf16x8*)((char*)SMEM + cur * 16384 + ra * 128 +
                                 (((kk * 4 + quad) ^ (ra & 7)) << 4));
        int rb = wn + t * 16 + l16;
        bfr[t] = *(const bf16x8*)((char*)SMEM + 32768 + cur * 16384 + rb * 128 +
                                  (((kk * 4 + quad) ^ (rb & 7)) << 4));
      }
#pragma unroll
      for (int mt = 0; mt < 4; ++mt)
#pragma unroll
        for (int nt = 0; nt < 4; ++nt)
          acc[mt][nt] = __builtin_amdgcn_mfma_f32_16x16x32_bf16(af[mt], bfr[nt], acc[mt][nt], 0, 0, 0);
    }
    __syncthreads();
  }

  unsigned short* E = SMEM;   // [128][136]
  if (isK) {
#pragma unroll
    for (int mt = 0; mt < 4; ++mt)
#pragma unroll
      for (int nt = 0; nt < 4; ++nt) {
        int ml = wm + mt * 16 + quad * 4;
        int d = wn + nt * 16 + l16;
#pragma unroll
        for (int r = 0; r < 4; ++r)
          E[(ml + r) * 136 + d] = f2bf(acc[mt][nt][r]);
      }
  } else {
#pragma unroll
    for (int mt = 0; mt < 4; ++mt)
#pragma unroll
      for (int nt = 0; nt < 4; ++nt) {
        int ml = wm + mt * 16 + quad * 4;
        int nl = wn + nt * 16 + l16;
#pragma unroll
        for (int r = 0; r < 4; ++r)
          E[nl * 136 + ml + r] = f2bf(acc[mt][nt][r]);
      }
  }
  __syncthreads();

  if (isK) {
    const int h = by;
#pragma unroll
    for (int i = 0; i < 8; ++i) {
      int idx = (i * 256 + tid) * 8;
      int row = idx >> 7, col = idx & 127;
      uint4 v = *(const uint4*)&E[row * 136 + col];
      *(uint4*)&Kb[(size_t)h * (T_SEQ * DQK) + (size_t)(m0 + row) * DQK + col] = v;
    }
    for (int e = tid; e < 128 * 16; e += 256) {
      int row = e >> 4, c4 = (e & 15) * 4;
      float4 v = *(const float4*)&k_pe[(size_t)(m0 + row) * DROPE + c4];
      ushort4 o = {f2bf(v.x), f2bf(v.y), f2bf(v.z), f2bf(v.w)};
      *(ushort4*)&Kb[(size_t)h * (T_SEQ * DQK) + (size_t)(m0 + row) * DQK + DNOPE + c4] = o;
    }
  } else {
#pragma unroll
    for (int i = 0; i < 8; ++i) {
      int idx = (i * 256 + tid) * 8;
      int row = idx >> 7, col = idx & 127;
      uint4 v = *(const uint4*)&E[row * 136 + col];
      *(uint4*)&Vt[(size_t)(n0 + row) * T_SEQ + m0 + col] = v;
    }
  }
}

// ---------------------------------------------------------------------------
// flash_mfma: R11/R13 (session-best: 60-62 us, MfmaUtil 13.5%, VGPR 52, LDS
// 40960 B = 4 blocks/CU). Swapped-QK (S^T = K @ Q^T) + sigma-permuted K
// staging -> softmax->PV fragment forms with ZERO cross-lane ops: LDS K row
//   rho<16 : kv = 8*(rho>>2) + 2*(rho&3)        (sacc0[r] -> kv quad*8+2r)
//   rho>=16: kv = 8*(rho'>>2) + 2*(rho'&3) + 1  (sacc1[r] -> kv quad*8+2r+1)
// so the PV A-fragment is 4x v_cvt_pk_bf16_f32 (bit-identical RNE). Async
// global_load_lds K/V dbuf with both-sides XOR swizzle, 1 barrier/chunk,
// work-proportional split-K, dense partial slots, no-max softmax, setprio.
// ---------------------------------------------------------------------------
__global__ __launch_bounds__(256, 4) void flash_mfma(
    const float* __restrict__ Q, const unsigned short* __restrict__ K,
    const unsigned short* __restrict__ Vt, float* __restrict__ outp,
    float* __restrict__ Opart, float* __restrict__ Lpart, int adaptive)
{
  __shared__ unsigned short SM[2 * KC * DQK];     // K dbuf [2][32][192]; Q stage [64][192]
  __shared__ unsigned short Vsm[2 * VDIM * KC];   // V dbuf [2][128][32]
  const int id = blockIdx.x;
  const int h = ((id & 7) << 1) | ((id >> 3) & 1);   // cluster heads per XCD
  int q0, c0, c1, slot, direct;
  if (adaptive) {
    const int b = 79 - (id >> 4);                    // heavy splits first
    int j, sp, s;
    if (b < 8)       { j = b;               sp = 0;            s = 1; }
    else if (b < 24) { j = 8 + (b - 8) / 2; sp = (b - 8) % 2;  s = 2; }
    else if (b < 48) { j = 16 + (b - 24) / 3; sp = (b - 24) % 3; s = 3; }
    else             { j = 24 + (b - 48) / 4; sp = (b - 48) % 4; s = 4; }
    q0 = j * 64;
    const int n = 2 * j + 2;
    c0 = (n * sp) / s;
    c1 = (n * (sp + 1)) / s;
    direct = (s == 1);
    slot = h * 72 + (b - 8);                         // valid iff !direct
  } else {
    q0 = (31 - (id >> 4)) * 64;
    c0 = 0; c1 = q0 / KC + 2; direct = 1; slot = 0;
  }
  const int tid = threadIdx.x;
  const int wid = tid >> 6;
  const int lane = tid & 63;
  const int l16 = lane & 15;
  const int quad = lane >> 4;
  const int myrow = q0 + wid * 16 + quad * 4;        // output-row base (D rows)
  const int qrow  = q0 + wid * 16 + l16;             // this lane's q in S^T
  const int nch = c1 - c0;                           // >= 1 always

  const unsigned short* Kh = K + (size_t)h * T_SEQ * DQK;
  const unsigned short* Vth = Vt + (size_t)h * VDIM * T_SEQ;

  // ---- precomputed per-thread staging offsets. K carries the sigma row
  //      permutation AND the inverse XOR swizzle on the SOURCE address. ----
  int ksrc_off[3], kdst_off[3];
#pragma unroll
  for (int i = 0; i < 3; ++i) {
    int d = tid * 16 + i * 4096;
    int rho = d / 384, c = d - rho * 384;
    int rr = rho & 15, hi = rho >> 4;                // hi: 0 -> even-slot kv
    int g = 8 * (rr >> 2) + 2 * (rr & 3) + hi;       // sigma(rho)
    ksrc_off[i] = g * 384 + (c ^ ((rho & 7) << 4));
    kdst_off[i] = d;
  }
  size_t vsrc_off[2]; int vdst_off[2];
#pragma unroll
  for (int i = 0; i < 2; ++i) {
    int d = tid * 16 + i * 4096;
    int row = d >> 6, c = d & 63;
    vsrc_off[i] = (size_t)row * (T_SEQ * 2) + (c ^ ((row & 3) << 4));
    vdst_off[i] = d;
  }

  auto stage = [&](int buf, int s0) {
    const char* Kc = (const char*)Kh + (size_t)s0 * 384;
    char* Kd = (char*)&SM[buf * (KC * DQK)];
#pragma unroll
    for (int i = 0; i < 3; ++i)
      __builtin_amdgcn_global_load_lds(
          (const unsigned int*)(Kc + ksrc_off[i]),
          (unsigned int*)(Kd + kdst_off[i]), 16, 0, 0);
    const char* Vc = (const char*)Vth + (size_t)s0 * 2;
    char* Vd = (char*)&Vsm[buf * (VDIM * KC)];
#pragma unroll
    for (int i = 0; i < 2; ++i)
      __builtin_amdgcn_global_load_lds(
          (const unsigned int*)(Vc + vsrc_off[i]),
          (unsigned int*)(Vd + vdst_off[i]), 16, 0, 0);
  };

  // ---- stage Q through the K-dbuf region (exactly 64*192 shorts) ----
  for (int e = tid; e < 64 * 48; e += 256) {
    int row = e / 48, col = (e % 48) * 4;
    float4 q4 = *(const float4*)&Q[(size_t)(q0 + row) * (NHEAD * DQK) + h * DQK + col];
    ushort4 qp = {f2bf(q4.x), f2bf(q4.y), f2bf(q4.z), f2bf(q4.w)};
    *(ushort4*)&SM[row * DQK + col] = qp;
  }
  __syncthreads();
  bf16x8 qf[6];
#pragma unroll
  for (int ks = 0; ks < 6; ++ks)
    qf[ks] = *(const bf16x8*)&SM[(wid * 16 + l16) * DQK + ks * 32 + quad * 8];
  __syncthreads();           // Q reads done before region becomes K buffers
  stage(0, c0 * KC);         // async chunk 0
  __syncthreads();           // drains vmcnt(0): buffer 0 visible

  f32x4 oacc[8];
#pragma unroll
  for (int i = 0; i < 8; ++i) oacc[i] = (f32x4){0.f, 0.f, 0.f, 0.f};
  float lsum = 0.f;          // per-lane: all kv for q = qrow (kv on quad axis)

  for (int ck = 0; ck < nch; ++ck) {
    const int cur = ck & 1;
    const int s0 = (c0 + ck) * KC;
    if (ck + 1 < nch) stage(cur ^ 1, s0 + KC);   // async, in flight all chunk

    // ---- S^T = K @ Q^T (swapped operands; sigma-permuted K rows) ----
    const char* Kbase = (const char*)&SM[cur * (KC * DQK)];
    f32x4 sacc0 = (f32x4){0.f, 0.f, 0.f, 0.f};
    f32x4 sacc1 = (f32x4){0.f, 0.f, 0.f, 0.f};
    __builtin_amdgcn_s_setprio(1);
#pragma unroll
    for (int ks = 0; ks < 6; ++ks) {
      int c = ks * 64 + quad * 16;
      int r0 = l16, r1 = 16 + l16;
      bf16x8 kf0 = *(const bf16x8*)(Kbase + r0 * 384 + (c ^ ((r0 & 7) << 4)));
      bf16x8 kf1 = *(const bf16x8*)(Kbase + r1 * 384 + (c ^ ((r1 & 7) << 4)));
      sacc0 = __builtin_amdgcn_mfma_f32_16x16x32_bf16(kf0, qf[ks], sacc0, 0, 0, 0);
      sacc1 = __builtin_amdgcn_mfma_f32_16x16x32_bf16(kf1, qf[ks], sacc1, 0, 0, 0);
    }
    __builtin_amdgcn_s_setprio(0);

    // ---- p = exp(s), mask via p=0. sigma: sacc0[r] -> kv s0+quad*8+2r,
    //      sacc1[r] -> kv s0+quad*8+2r+1. Pack directly into PV A-frag. ----
    union { unsigned int u[4]; bf16x8 v; } pw;
#pragma unroll
    for (int r = 0; r < 4; ++r) {
      int kva = s0 + quad * 8 + 2 * r;
      float e0 = (kva <= qrow)     ? __expf(sacc0[r] * SCALE_F) : 0.f;
      float e1 = (kva + 1 <= qrow) ? __expf(sacc1[r] * SCALE_F) : 0.f;
      lsum += e0 + e1;
      asm("v_cvt_pk_bf16_f32 %0, %1, %2" : "=v"(pw.u[r]) : "v"(e0), "v"(e1));
    }
    bf16x8 pf = pw.v;

    // ---- PV (D rows = quad*4+r -> same output layout as before) ----
    const char* Vbase = (const char*)&Vsm[cur * (VDIM * KC)];
    __builtin_amdgcn_s_setprio(1);
#pragma unroll
    for (int nt = 0; nt < 8; ++nt) {
      int vrow = nt * 16 + l16;
      bf16x8 vf = *(const bf16x8*)(Vbase + vrow * 64 + ((quad * 16) ^ ((vrow & 3) << 4)));
      oacc[nt] = __builtin_amdgcn_mfma_f32_16x16x32_bf16(pf, vf, oacc[nt], 0, 0, 0);
    }
    __builtin_amdgcn_s_setprio(0);

    __syncthreads();   // drains vmcnt (next-chunk stage) + lgkm; flip buffers
  }

  // ---- reduce lsum across quads (kv axis); all quads then hold q=l16 total --
  lsum += __shfl_xor(lsum, 16);
  lsum += __shfl_xor(lsum, 32);
  // redistribute to output-row layout: row r of this lane is q = quad*4+r
  float rowsum[4];
#pragma unroll
  for (int r = 0; r < 4; ++r) rowsum[r] = __shfl(lsum, quad * 4 + r, 64);

  if (direct) {
    float inv[4];
#pragma unroll
    for (int r = 0; r < 4; ++r) inv[r] = 1.f / rowsum[r];
#pragma unroll
    for (int nt = 0; nt < 8; ++nt)
#pragma unroll
      for (int r = 0; r < 4; ++r)
        outp[(size_t)(myrow + r) * (NHEAD * VDIM) + h * VDIM + nt * 16 + l16] =
            oacc[nt][r] * inv[r];
  } else {
    // dense block-local partial slot: [64][128] fp32, fully-written lines
    const int rbase = wid * 16 + quad * 4;
#pragma unroll
    for (int nt = 0; nt < 8; ++nt)
#pragma unroll
      for (int r = 0; r < 4; ++r)
        Opart[(size_t)slot * 8192 + (rbase + r) * 128 + nt * 16 + l16] =
            oacc[nt][r];
    if (l16 == 0)
#pragma unroll
      for (int r = 0; r < 4; ++r)
        Lpart[slot * 64 + rbase + r] = rowsum[r];
  }
}

// ---------------------------------------------------------------------------
// reduce_out: combine partial slots for split tiles (j >= 8 only).
// ---------------------------------------------------------------------------
__global__ __launch_bounds__(256) void reduce_out(
    const float* __restrict__ Opart, const float* __restrict__ Lpart,
    float* __restrict__ outp)
{
  const int t = blockIdx.x;
  const int h = t & 15;
  const int j = 8 + (t >> 4);
  int s, b0;
  if (j < 16)      { s = 2; b0 = 8 + (j - 8) * 2; }
  else if (j < 24) { s = 3; b0 = 24 + (j - 16) * 3; }
  else             { s = 4; b0 = 48 + (j - 24) * 4; }
  const int slot = h * 72 + (b0 - 8);
  const int q0 = j * 64;
  const int tid = threadIdx.x;
#pragma unroll
  for (int i = 0; i < 8; ++i) {
    const int f4 = tid + i * 256;            // [0,2048) float4 within tile
    const int row = f4 >> 5, cc = f4 & 31;
    float ax = 0.f, ay = 0.f, az = 0.f, aw = 0.f, l = 0.f;
    for (int k = 0; k < s; ++k) {
      float4 v = ((const float4*)Opart)[(size_t)(slot + k) * 2048 + f4];
      ax += v.x; ay += v.y; az += v.z; aw += v.w;
      l += Lpart[(slot + k) * 64 + row];
    }
    const float inv = 1.f / l;
    float4 o = {ax * inv, ay * inv, az * inv, aw * inv};
    ((float4*)outp)[(size_t)(q0 + row) * 512 + h * 32 + cc] = o;
  }
}

// ---------------------------------------------------------------------------
extern "C" void kernel_launch(void* const* d_in, const int* in_sizes, int n_in,
                              void* d_out, int out_size, void* d_ws, size_t ws_size,
                              hipStream_t stream) {
  const float* query  = (const float*)d_in[0];  // (T, H, 192)
  const float* k_c    = (const float*)d_in[1];  // (T, 512)
  const float* k_pe   = (const float*)d_in[2];  // (T, 64)
  const float* w_kv_b = (const float*)d_in[3];  // (512, 4096)
  const float* w_uv   = (const float*)d_in[4];  // (16, 512, 128)
  float* outp = (float*)d_out;                  // (T, 2048)

  unsigned short* Kb  = (unsigned short*)d_ws;             // (H,T,192) bf16
  unsigned short* Vt  = Kb + (size_t)NHEAD * T_SEQ * DQK;  // (H,128,T) bf16
  unsigned short* Ab  = Vt + (size_t)NHEAD * VDIM * T_SEQ; // (T,512)
  unsigned short* BkT = Ab + (size_t)T_SEQ * LORA_D;       // (2048,512)
  unsigned short* BvT = BkT + (size_t)2048 * LORA_D;       // (2048,512)
  float* Opart = (float*)(BvT + (size_t)2048 * LORA_D);    // 1152 x [64][128] fp32
  float* Lpart = Opart + (size_t)16 * 72 * 64 * 128;       // 1152 x [64] fp32
  const size_t need =
      (size_t)((char*)(Lpart + (size_t)16 * 72 * 64) - (char*)d_ws);
  const int adaptive = (ws_size >= need) ? 1 : 0;   // safe fallback

  stage_all<<<dim3(1024, 3), 256, 0, stream>>>(k_c, w_kv_b, w_uv, Ab, BkT, BvT);
  prep_gemm<<<dim3(16, 32), 256, 0, stream>>>(Ab, BkT, BvT, k_pe, Kb, Vt);
  flash_mfma<<<adaptive ? 1280 : 512, 256, 0, stream>>>(query, Kb, Vt, outp,
                                                        Opart, Lpart, adaptive);
  if (adaptive)
    reduce_out<<<384, 256, 0, stream>>>(Opart, Lpart, outp);
}